// Round 1
// baseline (1158.281 us; speedup 1.0000x reference)
//
#include <hip/hip_runtime.h>
#include <stdint.h>

// ---------------------------------------------------------------------------
// Fused MoE block on gfx950. Single persistent main kernel + tiny prep kernel.
// All GEMMs computed transposed (weights as MFMA A operand) so each lane owns
// exactly one token (lane&15) in every D fragment -> LN/router reductions are
// in-lane + 2 shuffles; stage-to-stage transpose is a 4-lane ds_bpermute.
// ---------------------------------------------------------------------------

typedef __attribute__((ext_vector_type(8))) short bf16x8;  // MFMA A/B operand
typedef __attribute__((ext_vector_type(4))) float f32x4;   // MFMA C/D operand

#define MFMA16(a, b, c) __builtin_amdgcn_mfma_f32_16x16x32_bf16((a), (b), (c), 0, 0, 0)

__device__ __forceinline__ uint32_t f2bf1(float f) {  // fp32 -> bf16 bits, RNE
  uint32_t u = __float_as_uint(f);
  return (u + 0x7FFFu + ((u >> 16) & 1u)) >> 16;
}

// exact-erf GELU via Abramowitz&Stegun 7.1.26 (|err| <= 1.5e-7)
__device__ __forceinline__ float geluf(float x) {
  float ax = __builtin_fabsf(x);
  float z  = ax * 0.70710678118654752f;
  float t  = __builtin_amdgcn_rcpf(__builtin_fmaf(0.3275911f, z, 1.0f));
  float p  = __builtin_fmaf(1.061405429f, t, -1.453152027f);
  p = __builtin_fmaf(p, t, 1.421413741f);
  p = __builtin_fmaf(p, t, -0.284496736f);
  p = __builtin_fmaf(p, t, 0.254829592f);
  p = p * t;
  float e  = __builtin_amdgcn_exp2f(-1.4426950408889634f * z * z);
  float er = __builtin_fmaf(-p, e, 1.0f);  // |erf(z)|
  return __builtin_fmaf(0.5f * ax, er, 0.5f * x);
}

__device__ __forceinline__ float sel_bperm(int ad, float a, float b, bool qhi) {
  int xa = __builtin_amdgcn_ds_bpermute(ad, __float_as_int(a));
  int xb = __builtin_amdgcn_ds_bpermute(ad, __float_as_int(b));
  return __int_as_float(qhi ? xb : xa);
}

// D-layout fp32 (token=lane&15, dim = mt*16 + q*4 + r)  ->  B-frag bf16
// (token=lane&15, k = c*32 + q*8 + i).  src lane = ((q&1)*2 + (i>>2))*16 + t,
// src reg = V[2c + (q>>1)][i&3].
__device__ __forceinline__ void xpose(const f32x4 (&V)[8], bf16x8 (&F)[4],
                                      int addr0, int addr1, bool qhi) {
#pragma unroll
  for (int c = 0; c < 4; ++c) {
    union { bf16x8 v; uint32_t u4[4]; } cv;
#pragma unroll
    for (int ii = 0; ii < 4; ++ii) {
      const int hi = ii >> 1;
      const int r0 = (ii & 1) * 2;
      const int ad = hi ? addr1 : addr0;
      float a0 = sel_bperm(ad, V[2 * c][r0],     V[2 * c + 1][r0],     qhi);
      float a1 = sel_bperm(ad, V[2 * c][r0 + 1], V[2 * c + 1][r0 + 1], qhi);
      cv.u4[ii] = f2bf1(a0) | (f2bf1(a1) << 16);
    }
    F[c] = cv.v;
  }
}

// ---------------------------------------------------------------------------
// prep: build bf16 A-fragment tables in ws.
// Layout (uint16 units): [0,16384) entry_w | [16384,81920) exp_w e=0..3 |
// [81920,98304) out_w.  Within a matrix: tile = mt*4+c (512 shorts), element
// lane*8+j = W[k=c*32+(lane>>4)*8+j][m=mt*16+(lane&15)].
// ---------------------------------------------------------------------------
__global__ void prep_frags(const float* __restrict__ w1,
                           const float* __restrict__ ew,
                           const float* __restrict__ ow,
                           uint16_t* __restrict__ ftab) {
  int idx = blockIdx.x * 256 + threadIdx.x;
  if (idx >= 98304) return;
  const float* mat;
  int rel;
  if (idx < 16384) { mat = w1; rel = idx; }
  else if (idx < 81920) {
    int e = (idx - 16384) >> 14;
    rel = (idx - 16384) & 16383;
    mat = ew + e * 16384;
  } else { mat = ow; rel = idx - 81920; }
  int tilei = rel >> 9;
  int ln    = (rel >> 3) & 63;
  int j     = rel & 7;
  int mt = tilei >> 2, c = tilei & 3;
  int k = c * 32 + ((ln >> 4) << 3) + j;
  int m = mt * 16 + (ln & 15);
  ftab[idx] = (uint16_t)f2bf1(mat[k * 128 + m]);
}

// ---------------------------------------------------------------------------
// main fused kernel: 256 blocks x 512 threads (8 waves), 1 block/CU.
// LDS: exp_w fragment table (131072 B), loaded once, read-only after.
// Each wave processes 32-token tiles (two 16-token N-subtiles).
// ---------------------------------------------------------------------------
__global__ __launch_bounds__(512, 2) void moe_main(
    const float* __restrict__ x, const float* __restrict__ eb,
    const float* __restrict__ rw, const float* __restrict__ rb,
    const float* __restrict__ expb, const float* __restrict__ lng,
    const float* __restrict__ lnb, const float* __restrict__ ob,
    const uint16_t* __restrict__ ftab, float* __restrict__ out, int ntiles) {
  extern __shared__ uint16_t lds_u16[];

  {  // stage exp_w frags -> LDS (contiguous copy)
    const uint4* src = (const uint4*)(ftab + 16384);
    uint4* dst = (uint4*)lds_u16;
    for (int i = threadIdx.x; i < 8192; i += 512) dst[i] = src[i];
  }
  __syncthreads();

  const int lane = threadIdx.x & 63;
  const int wave = threadIdx.x >> 6;
  const int q    = lane >> 4;
  const int tq   = lane & 15;
  const bool qhi = q >= 2;
  const int addr0 = ((((q & 1) << 1) << 4) + tq) << 2;  // ((q&1)*2*16+tq)*4
  const int addr1 = addr0 + 64;

  const bf16x8* w1f = (const bf16x8*)ftab;             // entry_w frags (L2)
  const bf16x8* owf = (const bf16x8*)(ftab + 81920);   // out_w frags (L2)
  const bf16x8* ef  = (const bf16x8*)lds_u16;          // exp_w frags (LDS)

  const int stride = gridDim.x * 8;
  for (int tile = blockIdx.x * 8 + wave; tile < ntiles; tile += stride) {
    const int t0 = tile * 32;

    // ---- load x as B-frags (xT), fp32 -> bf16 RNE ----
    bf16x8 xB[2][4];
#pragma unroll
    for (int s = 0; s < 2; ++s) {
      const float* xr = x + (size_t)(t0 + s * 16 + tq) * 128 + q * 8;
#pragma unroll
      for (int c = 0; c < 4; ++c) {
        f32x4 v0 = *(const f32x4*)(xr + c * 32);
        f32x4 v1 = *(const f32x4*)(xr + c * 32 + 4);
        union { bf16x8 v; uint32_t u4[4]; } cv;
        cv.u4[0] = f2bf1(v0[0]) | (f2bf1(v0[1]) << 16);
        cv.u4[1] = f2bf1(v0[2]) | (f2bf1(v0[3]) << 16);
        cv.u4[2] = f2bf1(v1[0]) | (f2bf1(v1[1]) << 16);
        cv.u4[3] = f2bf1(v1[2]) | (f2bf1(v1[3]) << 16);
        xB[s][c] = cv.v;
      }
    }

    // ---- entry GEMM: hT = W1T @ xT ----
    f32x4 h[2][8];
#pragma unroll
    for (int mt = 0; mt < 8; ++mt) { h[0][mt] = {0,0,0,0}; h[1][mt] = {0,0,0,0}; }
#pragma unroll
    for (int c = 0; c < 4; ++c) {
#pragma unroll
      for (int mt = 0; mt < 8; ++mt) {
        bf16x8 a = w1f[(mt * 4 + c) * 64 + lane];
        h[0][mt] = MFMA16(a, xB[0][c], h[0][mt]);
        h[1][mt] = MFMA16(a, xB[1][c], h[1][mt]);
      }
    }

    // ---- bias + GELU (fp32) + router logits (fp32 h, fp32 rw) ----
    float lg[2][4] = {{0, 0, 0, 0}, {0, 0, 0, 0}};
#pragma unroll
    for (int mt = 0; mt < 8; ++mt) {
      f32x4 bb = *(const f32x4*)(eb + mt * 16 + q * 4);
#pragma unroll
      for (int r = 0; r < 4; ++r) {
        f32x4 rwv = *(const f32x4*)(rw + (mt * 16 + q * 4 + r) * 4);
#pragma unroll
        for (int s = 0; s < 2; ++s) {
          float v = geluf(h[s][mt][r] + bb[r]);
          h[s][mt][r] = v;
#pragma unroll
          for (int e = 0; e < 4; ++e) lg[s][e] = __builtin_fmaf(v, rwv[e], lg[s][e]);
        }
      }
    }

    // ---- router reduce (lanes t, t^16, t^32, t^48 hold all 128 dims) + softmax
    float wgt[2][4];
#pragma unroll
    for (int s = 0; s < 2; ++s) {
#pragma unroll
      for (int e = 0; e < 4; ++e) {
        float v = lg[s][e];
        v += __shfl_xor(v, 16);
        v += __shfl_xor(v, 32);
        lg[s][e] = v + rb[e];
      }
      float m = fmaxf(fmaxf(lg[s][0], lg[s][1]), fmaxf(lg[s][2], lg[s][3]));
      float ex0 = __builtin_amdgcn_exp2f((lg[s][0] - m) * 1.4426950408889634f);
      float ex1 = __builtin_amdgcn_exp2f((lg[s][1] - m) * 1.4426950408889634f);
      float ex2 = __builtin_amdgcn_exp2f((lg[s][2] - m) * 1.4426950408889634f);
      float ex3 = __builtin_amdgcn_exp2f((lg[s][3] - m) * 1.4426950408889634f);
      float inv = __builtin_amdgcn_rcpf(ex0 + ex1 + ex2 + ex3);
      wgt[s][0] = ex0 * inv; wgt[s][1] = ex1 * inv;
      wgt[s][2] = ex2 * inv; wgt[s][3] = ex3 * inv;
    }

    // ---- transpose h (D-layout) -> B-frags for expert GEMMs ----
    bf16x8 hB[2][4];
    xpose(h[0], hB[0], addr0, addr1, qhi);
    xpose(h[1], hB[1], addr0, addr1, qhi);

    // ---- experts: eoT = WeT @ hT, GELU, LN, weighted combine ----
    f32x4 comb[2][8];
#pragma unroll
    for (int mt = 0; mt < 8; ++mt) { comb[0][mt] = {0,0,0,0}; comb[1][mt] = {0,0,0,0}; }

#pragma unroll
    for (int e = 0; e < 4; ++e) {
      f32x4 eo[2][8];
#pragma unroll
      for (int mt = 0; mt < 8; ++mt) { eo[0][mt] = {0,0,0,0}; eo[1][mt] = {0,0,0,0}; }
#pragma unroll
      for (int c = 0; c < 4; ++c) {
#pragma unroll
        for (int mt = 0; mt < 8; ++mt) {
          bf16x8 a = ef[(e * 32 + mt * 4 + c) * 64 + lane];
          eo[0][mt] = MFMA16(a, hB[0][c], eo[0][mt]);
          eo[1][mt] = MFMA16(a, hB[1][c], eo[1][mt]);
        }
      }
#pragma unroll
      for (int s = 0; s < 2; ++s) {
        float s1 = 0.f, s2 = 0.f;
#pragma unroll
        for (int mt = 0; mt < 8; ++mt) {
          f32x4 bb = *(const f32x4*)(expb + e * 128 + mt * 16 + q * 4);
#pragma unroll
          for (int r = 0; r < 4; ++r) {
            float v = geluf(eo[s][mt][r] + bb[r]);
            eo[s][mt][r] = v;
            s1 += v;
            s2 = __builtin_fmaf(v, v, s2);
          }
        }
        s1 += __shfl_xor(s1, 16); s1 += __shfl_xor(s1, 32);
        s2 += __shfl_xor(s2, 16); s2 += __shfl_xor(s2, 32);
        float mu   = s1 * 0.0078125f;
        float var  = __builtin_fmaf(s2, 0.0078125f, -mu * mu);
        float rstd = __builtin_amdgcn_rsqf(var + 1e-5f);
        float wk   = wgt[s][e];
#pragma unroll
        for (int mt = 0; mt < 8; ++mt) {
          f32x4 g = *(const f32x4*)(lng + e * 128 + mt * 16 + q * 4);
          f32x4 b = *(const f32x4*)(lnb + e * 128 + mt * 16 + q * 4);
#pragma unroll
          for (int r = 0; r < 4; ++r) {
            float v = (eo[s][mt][r] - mu) * rstd;
            v = __builtin_fmaf(v, g[r], b[r]);
            comb[s][mt][r] = __builtin_fmaf(wk, v, comb[s][mt][r]);
          }
        }
      }
    }

    // ---- transpose combined -> B-frags; out GEMM: outT = WoT @ combT ----
    bf16x8 cB[2][4];
    xpose(comb[0], cB[0], addr0, addr1, qhi);
    xpose(comb[1], cB[1], addr0, addr1, qhi);

    f32x4 oacc[2][8];
#pragma unroll
    for (int mt = 0; mt < 8; ++mt) { oacc[0][mt] = {0,0,0,0}; oacc[1][mt] = {0,0,0,0}; }
#pragma unroll
    for (int c = 0; c < 4; ++c) {
#pragma unroll
      for (int mt = 0; mt < 8; ++mt) {
        bf16x8 a = owf[(mt * 4 + c) * 64 + lane];
        oacc[0][mt] = MFMA16(a, cB[0][c], oacc[0][mt]);
        oacc[1][mt] = MFMA16(a, cB[1][c], oacc[1][mt]);
      }
    }

    // ---- bias + store (float4, fully covering each token row) ----
#pragma unroll
    for (int mt = 0; mt < 8; ++mt) {
      f32x4 bo = *(const f32x4*)(ob + mt * 16 + q * 4);
#pragma unroll
      for (int s = 0; s < 2; ++s) {
        f32x4 v = oacc[s][mt] + bo;
        *(f32x4*)(out + (size_t)(t0 + s * 16 + tq) * 128 + mt * 16 + q * 4) = v;
      }
    }
  }
}

extern "C" void kernel_launch(void* const* d_in, const int* in_sizes, int n_in,
                              void* d_out, int out_size, void* d_ws, size_t ws_size,
                              hipStream_t stream) {
  const float* x    = (const float*)d_in[0];
  const float* w1   = (const float*)d_in[1];
  const float* eb   = (const float*)d_in[2];
  const float* rw   = (const float*)d_in[3];
  const float* rb   = (const float*)d_in[4];
  const float* ew   = (const float*)d_in[5];
  const float* expb = (const float*)d_in[6];
  const float* lng  = (const float*)d_in[7];
  const float* lnb  = (const float*)d_in[8];
  const float* ow   = (const float*)d_in[9];
  const float* ob   = (const float*)d_in[10];
  float* out = (float*)d_out;
  uint16_t* ftab = (uint16_t*)d_ws;  // 196608 bytes used

  int ntok   = in_sizes[0] / 128;
  int ntiles = ntok / 32;

  hipLaunchKernelGGL(prep_frags, dim3(384), dim3(256), 0, stream, w1, ew, ow, ftab);

  // opt-in to 128 KiB dynamic LDS (idempotent; not a stream op)
  (void)hipFuncSetAttribute((const void*)moe_main,
                            hipFuncAttributeMaxDynamicSharedMemorySize, 131072);

  hipLaunchKernelGGL(moe_main, dim3(256), dim3(512), 131072, stream,
                     x, eb, rw, rb, expb, lng, lnb, ob,
                     (const uint16_t*)ftab, out, ntiles);
}